// Round 6
// baseline (8715.091 us; speedup 1.0000x reference)
//
#include <hip/hip_runtime.h>
#include <hip/hip_fp16.h>

typedef _Float16 f16;
typedef _Float16 f16x2 __attribute__((ext_vector_type(2)));
typedef _Float16 f16x4 __attribute__((ext_vector_type(4)));
typedef _Float16 f16x8 __attribute__((ext_vector_type(8)));
typedef float    f32x4 __attribute__((ext_vector_type(4)));

#define DEVI __device__ __forceinline__

DEVI float fdot2v(f16x2 a, f16x2 b, float c){
#if __has_builtin(__builtin_amdgcn_fdot2)
  return __builtin_amdgcn_fdot2(a, b, c, false);
#else
  return c + (float)a.x * (float)b.x + (float)a.y * (float)b.y;
#endif
}
DEVI f32x4 MM(f16x8 a, f16x8 b, f32x4 c){
  return __builtin_amdgcn_mfma_f32_16x16x32_f16(a, b, c, 0, 0, 0);
}
DEVI float tanh_f(float x){ return 1.f - 2.f / (__expf(2.f * x) + 1.f); }
DEVI float sigm_f(float x){ return 1.f / (1.f + __expf(-x)); }
DEVI float leaky_f(float x){ return x >= 0.f ? x : x * (1.0f / 5.5f); }

DEVI f16x8 ld8(const f16* p){ return *(const f16x8*)p; }

// A-fragment loader for mfma_f32_16x16x32_f16.
// lane holds A[m = MT + (lane&15)][k = ks*32 + (lane>>4)*8 + j], j=0..7, with a
// virtual column map: c<Kreal -> W[m*stride + c + coff]; c==tc0||tc1 -> W[m*stride]
// (t-weight, col 0); c==bc -> bias[m]; else 0. Rows >= rows -> 0.
DEVI f16x8 afrag(const float* W, const float* bias, int rows, int stride,
                 int Kreal, int coff, int tc0, int tc1, int bc,
                 int MT, int ks, int lane){
  int m  = MT + (lane & 15);
  int k0 = ks * 32 + ((lane >> 4) << 3);
  f16x8 v;
#pragma unroll
  for (int j = 0; j < 8; j++){
    int c = k0 + j; float x = 0.f;
    if (m < rows){
      if (c < Kreal)               x = W[m * stride + c + coff];
      else if (c == tc0 || c == tc1) x = W[m * stride];
      else if (c == bc)            x = bias[m];
    }
    v[j] = (f16)x;
  }
  return v;
}

// Epilogue: act(d[r]) -> f16 store to dst[0..3] (rows m0..m0+3), guarded by limit.
DEVI void epi(f16* dst, f32x4 d, int m0, int limit, bool lk){
  float v0 = lk ? leaky_f(d[0]) : tanh_f(d[0]);
  float v1 = lk ? leaky_f(d[1]) : tanh_f(d[1]);
  float v2 = lk ? leaky_f(d[2]) : tanh_f(d[2]);
  float v3 = lk ? leaky_f(d[3]) : tanh_f(d[3]);
  if (m0 + 4 <= limit){
    f16x4 s; s[0]=(f16)v0; s[1]=(f16)v1; s[2]=(f16)v2; s[3]=(f16)v3;
    *(f16x4*)dst = s;
  } else {
    if (m0 + 0 < limit) dst[0] = (f16)v0;
    if (m0 + 1 < limit) dst[1] = (f16)v1;
    if (m0 + 2 < limit) dst[2] = (f16)v2;
    if (m0 + 3 < limit) dst[3] = (f16)v3;
  }
}

// strides (elements)
#define XIN_S 136   // f16: k 0..99=y, 100=t_hi, 101=t_lo, 102=1.0, rest pad(0)
#define X12_S 296   // f16: k 0..274=act, 275=1.0(bias), rest pad(0)
#define YF_S  116   // f32
#define O_S   104   // f16: k 0..74=act, 75=1.0, rest pad(0)
#define GH_S  312   // f16
#define PA_S  64

// ===================== Kernel 1: encoder + latent MLP =====================
__global__ __launch_bounds__(512) void k_encode(
    const float* __restrict__ past, const float* __restrict__ h0,
    const float* __restrict__ fW1, const float* __restrict__ fb1,
    const float* __restrict__ fW2, const float* __restrict__ fb2,
    const float* __restrict__ fW3, const float* __restrict__ fb3,
    const float* __restrict__ Wih, const float* __restrict__ Whh,
    const float* __restrict__ bih, const float* __restrict__ bhh,
    const float* __restrict__ gW1, const float* __restrict__ gb1,
    const float* __restrict__ gW2, const float* __restrict__ gb2,
    const float* __restrict__ gW3, const float* __restrict__ gb3,
    float* __restrict__ gxws)
{
  __shared__ alignas(16) f16   xin[16 * XIN_S];
  __shared__ alignas(16) f16   x1s[16 * X12_S];
  __shared__ alignas(16) f16   x2s[16 * X12_S];
  __shared__ alignas(16) float yfs[16 * YF_S];
  __shared__ alignas(16) float kas[16 * YF_S];
  __shared__ alignas(16) f16   ghs[16 * GH_S];
  __shared__ alignas(16) float pas[16 * PA_S];
  __shared__ alignas(16) float wihL[300];
  __shared__ alignas(16) float bihL[300];

  const int tid = threadIdx.x, blk = blockIdx.x;
  const int lane = tid & 63, w = tid >> 6;
  const int q = lane >> 4, n16 = lane & 15;
  const int bq = q * 8;

  const int t0i = w, t1i = w + 8;
  const int t2i = (w == 6) ? 16 : (w == 7) ? 17 : -1;
  const int mt3 = (w < 7) ? w : -1;

  // field weight fragments (registers)
  f16x8 w1f[3][4], w2f[3][9], w3f[9];
#pragma unroll
  for (int ks = 0; ks < 4; ks++){
    w1f[0][ks] = afrag(fW1, fb1, 275, 101, 100, 1, 100, 101, 102, t0i*16, ks, lane);
    w1f[1][ks] = afrag(fW1, fb1, 275, 101, 100, 1, 100, 101, 102, t1i*16, ks, lane);
    w1f[2][ks] = (t2i >= 0) ? afrag(fW1, fb1, 275, 101, 100, 1, 100, 101, 102, t2i*16, ks, lane) : (f16x8)(f16)0.f;
  }
#pragma unroll
  for (int ks = 0; ks < 9; ks++){
    w2f[0][ks] = afrag(fW2, fb2, 275, 275, 275, 0, -1, -1, 275, t0i*16, ks, lane);
    w2f[1][ks] = afrag(fW2, fb2, 275, 275, 275, 0, -1, -1, 275, t1i*16, ks, lane);
    w2f[2][ks] = (t2i >= 0) ? afrag(fW2, fb2, 275, 275, 275, 0, -1, -1, 275, t2i*16, ks, lane) : (f16x8)(f16)0.f;
    w3f[ks]    = (mt3 >= 0) ? afrag(fW3, fb3, 100, 275, 275, 0, -1, -1, 275, mt3*16, ks, lane) : (f16x8)(f16)0.f;
  }

  // ---- Phase A: zero all MFMA-read LDS; load small tables ----
  for (int i = tid; i < 16 * XIN_S; i += 512) xin[i] = (f16)0.f;
  for (int i = tid; i < 16 * X12_S; i += 512){ x1s[i] = (f16)0.f; x2s[i] = (f16)0.f; }
  for (int i = tid; i < 16 * 64; i += 512) pas[i] = past[blk * 1024 + i];
  for (int i = tid; i < 300; i += 512){ wihL[i] = Wih[i]; bihL[i] = bih[i]; }
  __syncthreads();
  // ---- Phase B: constants + y0 + t0 ----
  {
    int n = tid >> 5, j0 = tid & 31;
    int r = blk * 16 + n;
    for (int m = j0; m < 100; m += 32){
      float v = h0[r * 100 + m];
      yfs[n * YF_S + m] = v; xin[n * XIN_S + m] = (f16)v;
    }
  }
  if (tid < 16){
    xin[tid * XIN_S + 102] = (f16)1.f;
    x1s[tid * X12_S + 275] = (f16)1.f;
    x2s[tid * X12_S + 275] = (f16)1.f;
    float t0 = pas[tid * PA_S] - 1.f;
    f16 th = (f16)t0;
    xin[tid * XIN_S + 100] = th;
    xin[tid * XIN_S + 101] = (f16)(t0 - (float)th);
  }
  __syncthreads();

  const f16* xinL = xin + n16 * XIN_S;
  const f16* x1L  = x1s + n16 * X12_S;
  const f16* x2L  = x2s + n16 * X12_S;

#pragma unroll 1
  for (int st = 0; st < 32; st++){
#pragma unroll 1
    for (int g = 0; g < 8; g++){
      // ---- P1: stage 1 ----
      {
        f32x4 d0 = {0.f,0.f,0.f,0.f}, d1 = d0, d2 = d0;
#pragma unroll
        for (int ks = 0; ks < 4; ks++){
          f16x8 b = ld8(xinL + ks * 32 + bq);
          d0 = MM(w1f[0][ks], b, d0);
          d1 = MM(w1f[1][ks], b, d1);
          if (t2i >= 0) d2 = MM(w1f[2][ks], b, d2);
        }
        epi(x1s + n16 * X12_S + t0i * 16 + q * 4, d0, t0i * 16 + q * 4, 275, false);
        epi(x1s + n16 * X12_S + t1i * 16 + q * 4, d1, t1i * 16 + q * 4, 275, false);
        if (t2i >= 0) epi(x1s + n16 * X12_S + t2i * 16 + q * 4, d2, t2i * 16 + q * 4, 275, false);
      }
      __syncthreads();
      // ---- P2: stage 2 ----
      {
        f32x4 d0 = {0.f,0.f,0.f,0.f}, d1 = d0, d2 = d0;
#pragma unroll
        for (int ks = 0; ks < 9; ks++){
          f16x8 b = ld8(x1L + ks * 32 + bq);
          d0 = MM(w2f[0][ks], b, d0);
          d1 = MM(w2f[1][ks], b, d1);
          if (t2i >= 0) d2 = MM(w2f[2][ks], b, d2);
        }
        epi(x2s + n16 * X12_S + t0i * 16 + q * 4, d0, t0i * 16 + q * 4, 275, false);
        epi(x2s + n16 * X12_S + t1i * 16 + q * 4, d1, t1i * 16 + q * 4, 275, false);
        if (t2i >= 0) epi(x2s + n16 * X12_S + t2i * 16 + q * 4, d2, t2i * 16 + q * 4, 275, false);
      }
      __syncthreads();
      // ---- P3: stage 3 + RK glue ----
      {
        if (mt3 >= 0){
          f32x4 d = {0.f,0.f,0.f,0.f};
#pragma unroll
          for (int ks = 0; ks < 9; ks++){
            f16x8 b = ld8(x2L + ks * 32 + bq);
            d = MM(w3f[ks], b, d);
          }
          int m0 = mt3 * 16 + q * 4;
          if (m0 + 3 < 100){
            float tc = pas[n16 * PA_S + 2 * st];
            float tp = (st == 0) ? tc - 1.f : pas[n16 * PA_S + 2 * st - 2];
            float dt = (tc - tp) * 0.5f;
            f32x4 kv;
            kv[0] = tanh_f(d[0]); kv[1] = tanh_f(d[1]);
            kv[2] = tanh_f(d[2]); kv[3] = tanh_f(d[3]);
            float* yp = yfs + n16 * YF_S + m0;
            float* kp = kas + n16 * YF_S + m0;
            f16*   xp = xin + n16 * XIN_S + m0;
            f32x4 yv = *(f32x4*)yp;
            f32x4 yst;
            int e = g & 3;
            if (e == 0){ *(f32x4*)kp = kv;                 yst = yv + 0.5f * dt * kv; }
            else if (e == 1){ *(f32x4*)kp = *(f32x4*)kp + 2.f * kv; yst = yv + 0.5f * dt * kv; }
            else if (e == 2){ *(f32x4*)kp = *(f32x4*)kp + 2.f * kv; yst = yv + dt * kv; }
            else { f32x4 yn = yv + dt * (*(f32x4*)kp + kv) * (1.f / 6.f); *(f32x4*)yp = yn; yst = yn; }
            f16x4 xs; xs[0]=(f16)yst[0]; xs[1]=(f16)yst[1]; xs[2]=(f16)yst[2]; xs[3]=(f16)yst[3];
            *(f16x4*)xp = xs;
          }
        }
        if (tid < 16 && g < 7){
          int gn = g + 1;
          float tc = pas[tid * PA_S + 2 * st];
          float tp = (st == 0) ? tc - 1.f : pas[tid * PA_S + 2 * st - 2];
          float dt2 = (tc - tp) * 0.5f;
          float ce = (gn & 3) == 0 ? 0.f : ((gn & 3) == 3 ? 1.f : 0.5f);
          float t = tp + (float)(gn >> 2) * dt2 + ce * dt2;
          f16 th = (f16)t;
          xin[tid * XIN_S + 100] = th;
          xin[tid * XIN_S + 101] = (f16)(t - (float)th);
        }
      }
      __syncthreads();
    }
    // ---- P4: gh = Whh @ h (+bhh via bias col) ----
    {
      f16x8 b0 = ld8(xinL + 0 * 32 + bq), b1 = ld8(xinL + 1 * 32 + bq),
            b2 = ld8(xinL + 2 * 32 + bq), b3 = ld8(xinL + 3 * 32 + bq);
      int wt[3];
      wt[0] = (w < 6) ? w : (w == 6 ? 18 : -1);
      wt[1] = (w < 6) ? w + 6 : -1;
      wt[2] = (w < 6) ? w + 12 : -1;
#pragma unroll
      for (int ti = 0; ti < 3; ti++){
        if (wt[ti] < 0) continue;
        int MT = wt[ti] * 16;
        f32x4 d = {0.f,0.f,0.f,0.f};
        d = MM(afrag(Whh, bhh, 300, 100, 100, 0, -1, -1, 102, MT, 0, lane), b0, d);
        d = MM(afrag(Whh, bhh, 300, 100, 100, 0, -1, -1, 102, MT, 1, lane), b1, d);
        d = MM(afrag(Whh, bhh, 300, 100, 100, 0, -1, -1, 102, MT, 2, lane), b2, d);
        d = MM(afrag(Whh, bhh, 300, 100, 100, 0, -1, -1, 102, MT, 3, lane), b3, d);
        int m0 = MT + q * 4;
        if (m0 + 4 <= 300){
          f16x4 s; s[0]=(f16)d[0]; s[1]=(f16)d[1]; s[2]=(f16)d[2]; s[3]=(f16)d[3];
          *(f16x4*)(ghs + n16 * GH_S + m0) = s;
        }
      }
    }
    __syncthreads();
    // ---- P5: GRU gates ----
    {
      int n = tid >> 5, j0 = tid & 31;
      float x = pas[n * PA_S + 2 * st + 1];
#pragma unroll 1
      for (int j = j0; j < 100; j += 32){
        float ghr = (float)ghs[n * GH_S + j];
        float ghz = (float)ghs[n * GH_S + 100 + j];
        float ghn = (float)ghs[n * GH_S + 200 + j];
        float r = sigm_f(x * wihL[j]       + bihL[j]       + ghr);
        float z = sigm_f(x * wihL[100 + j] + bihL[100 + j] + ghz);
        float nn = tanh_f(x * wihL[200 + j] + bihL[200 + j] + r * ghn);
        float h = yfs[n * YF_S + j];
        float hn = (1.f - z) * nn + z * h;
        yfs[n * YF_S + j] = hn;
        xin[n * XIN_S + j] = (f16)hn;
      }
      if (tid < 16 && st < 31){
        float t = pas[tid * PA_S + 2 * st];   // next interval: tp' = times[st]
        f16 th = (f16)t;
        xin[tid * XIN_S + 100] = th;
        xin[tid * XIN_S + 101] = (f16)(t - (float)th);
      }
    }
    __syncthreads();
  }

  // ---- latent MLP (f32, runs once) ----
  float* o1f = (float*)x1s;   // 16*76 f32, fits (x1s alignas(16))
  float* o2f = (float*)x2s;
  for (int idx = tid; idx < 75 * 16; idx += 512){
    int j = idx >> 4, n = idx & 15;
    float a = gb1[j];
    for (int k = 0; k < 100; k++) a += gW1[j * 100 + k] * yfs[n * YF_S + k];
    o1f[n * 76 + j] = leaky_f(a);
  }
  __syncthreads();
  for (int idx = tid; idx < 75 * 16; idx += 512){
    int j = idx >> 4, n = idx & 15;
    float a = gb2[j];
    for (int k = 0; k < 75; k++) a += gW2[j * 75 + k] * o1f[n * 76 + k];
    o2f[n * 76 + j] = leaky_f(a);
  }
  __syncthreads();
  if (tid < 32){
    int j = tid >> 4, n = tid & 15;
    float a = gb3[j];
    for (int k = 0; k < 75; k++) a += gW3[j * 75 + k] * o2f[n * 76 + k];
    gxws[(blk * 16 + n) * 2 + j] = a;
  }
}

// ===================== Kernel 2: z0 + forecast ODE + decoder =====================
__global__ __launch_bounds__(512) void k_forecast(
    const float* __restrict__ t_future, const float* __restrict__ eps,
    const float* __restrict__ fW1, const float* __restrict__ fb1,
    const float* __restrict__ fW2, const float* __restrict__ fb2,
    const float* __restrict__ fW3, const float* __restrict__ fb3,
    const float* __restrict__ oW1, const float* __restrict__ ob1,
    const float* __restrict__ oW2, const float* __restrict__ ob2,
    const float* __restrict__ oW3, const float* __restrict__ ob3,
    const float* __restrict__ gxws, float* __restrict__ out)
{
  __shared__ alignas(16) f16   xin[16 * XIN_S];
  __shared__ alignas(16) f16   x1s[16 * X12_S];
  __shared__ alignas(16) f16   x2s[16 * X12_S];
  __shared__ alignas(16) float yfs[16 * YF_S];
  __shared__ alignas(16) float kas[16 * YF_S];
  __shared__ alignas(16) f16   o1s[16 * O_S];
  __shared__ alignas(16) f16   o2s[16 * O_S];
  __shared__ alignas(16) float tfs[16 * 256];
  __shared__ alignas(16) f16   ow3L[96];

  const int tid = threadIdx.x, blk = blockIdx.x;
  const int lane = tid & 63, w = tid >> 6;
  const int q = lane >> 4, n16 = lane & 15;
  const int bq = q * 8;

  const int t0i = w, t1i = w + 8;
  const int t2i = (w == 6) ? 16 : (w == 7) ? 17 : -1;
  const int mt3 = (w < 7) ? w : -1;
  const bool hasdec = (w < 5);

  f16x8 w1f[3][4], w2f[3][9], w3f[9];
#pragma unroll
  for (int ks = 0; ks < 4; ks++){
    w1f[0][ks] = afrag(fW1, fb1, 275, 101, 100, 1, 100, 101, 102, t0i*16, ks, lane);
    w1f[1][ks] = afrag(fW1, fb1, 275, 101, 100, 1, 100, 101, 102, t1i*16, ks, lane);
    w1f[2][ks] = (t2i >= 0) ? afrag(fW1, fb1, 275, 101, 100, 1, 100, 101, 102, t2i*16, ks, lane) : (f16x8)(f16)0.f;
  }
#pragma unroll
  for (int ks = 0; ks < 9; ks++){
    w2f[0][ks] = afrag(fW2, fb2, 275, 275, 275, 0, -1, -1, 275, t0i*16, ks, lane);
    w2f[1][ks] = afrag(fW2, fb2, 275, 275, 275, 0, -1, -1, 275, t1i*16, ks, lane);
    w2f[2][ks] = (t2i >= 0) ? afrag(fW2, fb2, 275, 275, 275, 0, -1, -1, 275, t2i*16, ks, lane) : (f16x8)(f16)0.f;
    w3f[ks]    = (mt3 >= 0) ? afrag(fW3, fb3, 100, 275, 275, 0, -1, -1, 275, mt3*16, ks, lane) : (f16x8)(f16)0.f;
  }
  const float ob3v = ob3[0];

  // ---- Phase A: zero all MFMA/fdot-read LDS; load tfs ----
  for (int i = tid; i < 16 * XIN_S; i += 512) xin[i] = (f16)0.f;
  for (int i = tid; i < 16 * X12_S; i += 512){ x1s[i] = (f16)0.f; x2s[i] = (f16)0.f; }
  for (int i = tid; i < 16 * O_S; i += 512){ o1s[i] = (f16)0.f; o2s[i] = (f16)0.f; }
  for (int i = tid; i < 16 * 256; i += 512) tfs[i] = t_future[blk * 4096 + i];
  if (tid < 96) ow3L[tid] = (tid < 75) ? (f16)oW3[tid] : (f16)0.f;
  __syncthreads();
  // ---- Phase B: constants + z0 + t0 ----
  {
    int n = tid >> 5, j0 = tid & 31;
    int r = blk * 16 + n;
    float loc, scl;
    if (r < 128){ loc = gxws[4 * r];           scl = gxws[4 * r + 2]; }
    else        { loc = fabsf(gxws[4 * r - 511]); scl = fabsf(gxws[4 * r - 509]); }
    for (int m = j0; m < 100; m += 32){
      float v = loc + scl * eps[m * 256 + r];
      yfs[n * YF_S + m] = v; xin[n * XIN_S + m] = (f16)v;
    }
  }
  if (tid < 16){
    xin[tid * XIN_S + 102] = (f16)1.f;
    x1s[tid * X12_S + 275] = (f16)1.f;
    x2s[tid * X12_S + 275] = (f16)1.f;
    o1s[tid * O_S + 75]    = (f16)1.f;
    float t0 = tfs[tid * 256];
    f16 th = (f16)t0;
    xin[tid * XIN_S + 100] = th;
    xin[tid * XIN_S + 101] = (f16)(t0 - (float)th);
  }
  __syncthreads();

  const f16* xinL = xin + n16 * XIN_S;
  const f16* x1L  = x1s + n16 * X12_S;
  const f16* x2L  = x2s + n16 * X12_S;
  const f16* o1L  = o1s + n16 * O_S;

#pragma unroll 1
  for (int iv = 0; iv < 255; iv++){
#pragma unroll 1
    for (int g = 0; g < 8; g++){
      const bool dec = (g == 0);
      // ---- P1: S1 (+decoder L1 on start-of-interval state) ----
      {
        f32x4 d0 = {0.f,0.f,0.f,0.f}, d1 = d0, d2 = d0, dd = d0;
        f16x8 ow1f[4];
        if (dec && hasdec){
#pragma unroll
          for (int ks = 0; ks < 4; ks++)
            ow1f[ks] = afrag(oW1, ob1, 75, 100, 100, 0, -1, -1, 102, w * 16, ks, lane);
        }
#pragma unroll
        for (int ks = 0; ks < 4; ks++){
          f16x8 b = ld8(xinL + ks * 32 + bq);
          d0 = MM(w1f[0][ks], b, d0);
          d1 = MM(w1f[1][ks], b, d1);
          if (t2i >= 0) d2 = MM(w1f[2][ks], b, d2);
          if (dec && hasdec) dd = MM(ow1f[ks], b, dd);
        }
        epi(x1s + n16 * X12_S + t0i * 16 + q * 4, d0, t0i * 16 + q * 4, 275, false);
        epi(x1s + n16 * X12_S + t1i * 16 + q * 4, d1, t1i * 16 + q * 4, 275, false);
        if (t2i >= 0) epi(x1s + n16 * X12_S + t2i * 16 + q * 4, d2, t2i * 16 + q * 4, 275, false);
        if (dec && hasdec) epi(o1s + n16 * O_S + w * 16 + q * 4, dd, w * 16 + q * 4, 75, true);
      }
      __syncthreads();
      // ---- P2: S2 (+decoder L2) ----
      {
        f32x4 d0 = {0.f,0.f,0.f,0.f}, d1 = d0, d2 = d0, dd = d0;
#pragma unroll
        for (int ks = 0; ks < 9; ks++){
          f16x8 b = ld8(x1L + ks * 32 + bq);
          d0 = MM(w2f[0][ks], b, d0);
          d1 = MM(w2f[1][ks], b, d1);
          if (t2i >= 0) d2 = MM(w2f[2][ks], b, d2);
        }
        if (dec && hasdec){
#pragma unroll
          for (int ks = 0; ks < 3; ks++){
            f16x8 ow2f = afrag(oW2, ob2, 75, 75, 75, 0, -1, -1, 75, w * 16, ks, lane);
            f16x8 b2 = ld8(o1L + ks * 32 + bq);
            dd = MM(ow2f, b2, dd);
          }
        }
        epi(x2s + n16 * X12_S + t0i * 16 + q * 4, d0, t0i * 16 + q * 4, 275, false);
        epi(x2s + n16 * X12_S + t1i * 16 + q * 4, d1, t1i * 16 + q * 4, 275, false);
        if (t2i >= 0) epi(x2s + n16 * X12_S + t2i * 16 + q * 4, d2, t2i * 16 + q * 4, 275, false);
        if (dec && hasdec) epi(o2s + n16 * O_S + w * 16 + q * 4, dd, w * 16 + q * 4, 75, true);
      }
      __syncthreads();
      // ---- P3: S3 + RK glue ; decoder L3 on wave 7 ----
      {
        if (mt3 >= 0){
          f32x4 d = {0.f,0.f,0.f,0.f};
#pragma unroll
          for (int ks = 0; ks < 9; ks++){
            f16x8 b = ld8(x2L + ks * 32 + bq);
            d = MM(w3f[ks], b, d);
          }
          int m0 = mt3 * 16 + q * 4;
          if (m0 + 3 < 100){
            float tp = tfs[n16 * 256 + iv], tc = tfs[n16 * 256 + iv + 1];
            float dt = (tc - tp) * 0.5f;
            f32x4 kv;
            kv[0] = tanh_f(d[0]); kv[1] = tanh_f(d[1]);
            kv[2] = tanh_f(d[2]); kv[3] = tanh_f(d[3]);
            float* yp = yfs + n16 * YF_S + m0;
            float* kp = kas + n16 * YF_S + m0;
            f16*   xp = xin + n16 * XIN_S + m0;
            f32x4 yv = *(f32x4*)yp;
            f32x4 yst;
            int e = g & 3;
            if (e == 0){ *(f32x4*)kp = kv;                       yst = yv + 0.5f * dt * kv; }
            else if (e == 1){ *(f32x4*)kp = *(f32x4*)kp + 2.f * kv; yst = yv + 0.5f * dt * kv; }
            else if (e == 2){ *(f32x4*)kp = *(f32x4*)kp + 2.f * kv; yst = yv + dt * kv; }
            else { f32x4 yn = yv + dt * (*(f32x4*)kp + kv) * (1.f / 6.f); *(f32x4*)yp = yn; yst = yn; }
            f16x4 xs; xs[0]=(f16)yst[0]; xs[1]=(f16)yst[1]; xs[2]=(f16)yst[2]; xs[3]=(f16)yst[3];
            *(f16x4*)xp = xs;
          }
        }
        if (tid < 16){
          int gn = g + 1, ivn = iv;
          if (gn == 8){ gn = 0; ivn = iv + 1; }
          if (ivn < 255){
            float tp = tfs[tid * 256 + ivn], tc = tfs[tid * 256 + ivn + 1];
            float dt2 = (tc - tp) * 0.5f;
            float ce = (gn & 3) == 0 ? 0.f : ((gn & 3) == 3 ? 1.f : 0.5f);
            float t = tp + (float)(gn >> 2) * dt2 + ce * dt2;
            f16 th = (f16)t;
            xin[tid * XIN_S + 100] = th;
            xin[tid * XIN_S + 101] = (f16)(t - (float)th);
          }
        }
        if (dec && w == 7){
          int nn = lane >> 2, p = lane & 3;
          float a = 0.f;
          const f16x2* wv = (const f16x2*)(ow3L + 24 * p);
          const f16x2* xv = (const f16x2*)(o2s + nn * O_S + 24 * p);
#pragma unroll
          for (int j = 0; j < 12; j++) a = fdot2v(wv[j], xv[j], a);
          a += __shfl_xor(a, 1); a += __shfl_xor(a, 2);
          if (p == 0) out[(blk * 16 + nn) * 256 + iv] = a + ob3v;
        }
      }
      __syncthreads();
    }
  }
  // ---- final decode: tf = 255 on the post-loop state ----
  {
    if (hasdec){
      f32x4 dd = {0.f,0.f,0.f,0.f};
#pragma unroll
      for (int ks = 0; ks < 4; ks++){
        f16x8 ow1f = afrag(oW1, ob1, 75, 100, 100, 0, -1, -1, 102, w * 16, ks, lane);
        f16x8 b = ld8(xinL + ks * 32 + bq);
        dd = MM(ow1f, b, dd);
      }
      epi(o1s + n16 * O_S + w * 16 + q * 4, dd, w * 16 + q * 4, 75, true);
    }
    __syncthreads();
    if (hasdec){
      f32x4 d2 = {0.f,0.f,0.f,0.f};
#pragma unroll
      for (int ks = 0; ks < 3; ks++){
        f16x8 ow2f = afrag(oW2, ob2, 75, 75, 75, 0, -1, -1, 75, w * 16, ks, lane);
        f16x8 b2 = ld8(o1L + ks * 32 + bq);
        d2 = MM(ow2f, b2, d2);
      }
      epi(o2s + n16 * O_S + w * 16 + q * 4, d2, w * 16 + q * 4, 75, true);
    }
    __syncthreads();
    if (w == 7){
      int nn = lane >> 2, p = lane & 3;
      float a = 0.f;
      const f16x2* wv = (const f16x2*)(ow3L + 24 * p);
      const f16x2* xv = (const f16x2*)(o2s + nn * O_S + 24 * p);
#pragma unroll
      for (int j = 0; j < 12; j++) a = fdot2v(wv[j], xv[j], a);
      a += __shfl_xor(a, 1); a += __shfl_xor(a, 2);
      if (p == 0) out[(blk * 16 + nn) * 256 + 255] = a + ob3v;
    }
  }
}

extern "C" void kernel_launch(void* const* d_in, const int* in_sizes, int n_in,
                              void* d_out, int out_size, void* d_ws, size_t ws_size,
                              hipStream_t stream) {
  (void)in_sizes; (void)n_in; (void)out_size; (void)ws_size;
  const float* past     = (const float*)d_in[0];
  const float* h0       = (const float*)d_in[1];
  const float* t_future = (const float*)d_in[2];
  const float* eps      = (const float*)d_in[3];
  const float* fW1 = (const float*)d_in[4];  const float* fb1 = (const float*)d_in[5];
  const float* fW2 = (const float*)d_in[6];  const float* fb2 = (const float*)d_in[7];
  const float* fW3 = (const float*)d_in[8];  const float* fb3 = (const float*)d_in[9];
  const float* Wih = (const float*)d_in[10]; const float* Whh = (const float*)d_in[11];
  const float* bih = (const float*)d_in[12]; const float* bhh = (const float*)d_in[13];
  const float* gW1 = (const float*)d_in[14]; const float* gb1 = (const float*)d_in[15];
  const float* gW2 = (const float*)d_in[16]; const float* gb2 = (const float*)d_in[17];
  const float* gW3 = (const float*)d_in[18]; const float* gb3 = (const float*)d_in[19];
  const float* oW1 = (const float*)d_in[20]; const float* ob1 = (const float*)d_in[21];
  const float* oW2 = (const float*)d_in[22]; const float* ob2 = (const float*)d_in[23];
  const float* oW3 = (const float*)d_in[24]; const float* ob3 = (const float*)d_in[25];
  float* gxws = (float*)d_ws;
  float* out = (float*)d_out;

  hipLaunchKernelGGL(k_encode, dim3(16), dim3(512), 0, stream,
      past, h0, fW1, fb1, fW2, fb2, fW3, fb3,
      Wih, Whh, bih, bhh, gW1, gb1, gW2, gb2, gW3, gb3, gxws);
  hipLaunchKernelGGL(k_forecast, dim3(16), dim3(512), 0, stream,
      t_future, eps, fW1, fb1, fW2, fb2, fW3, fb3,
      oW1, ob1, oW2, ob2, oW3, ob3, gxws, out);
}